// Round 1
// baseline (244.174 us; speedup 1.0000x reference)
//
#include <hip/hip_runtime.h>
#include <math.h>

#define D 1024
#define TOPK 32
#define VPT 16   // values per lane = D / 64
#define WPB 4    // waves (rows) per block -> 256 threads

__device__ __forceinline__ float waveReduceMax(float v) {
#pragma unroll
  for (int off = 32; off >= 1; off >>= 1)
    v = fmaxf(v, __shfl_xor(v, off, 64));
  return v;
}
__device__ __forceinline__ int waveReduceSumI(int v) {
#pragma unroll
  for (int off = 32; off >= 1; off >>= 1)
    v += __shfl_xor(v, off, 64);
  return v;
}
__device__ __forceinline__ float waveReduceSumF(float v) {
#pragma unroll
  for (int off = 32; off >= 1; off >>= 1)
    v += __shfl_xor(v, off, 64);
  return v;
}

// Hoist per-channel rsqrt(clip(var)) out of the main loop: 1024 channels once.
__global__ __launch_bounds__(256) void prep_stats(const float* __restrict__ ema_mean,
                                                  const float* __restrict__ ema_sq,
                                                  float* __restrict__ inv_std) {
  int i = blockIdx.x * 256 + threadIdx.x;
  if (i < D) {
    float m = ema_mean[i];
    float v = ema_sq[i] - m * m;
    inv_std[i] = rsqrtf(fmaxf(v, 1e-6f));
  }
}

__global__ __launch_bounds__(256) void gelu_gate(const float* __restrict__ x,
                                                 const float* __restrict__ p_la,
                                                 const float* __restrict__ p_ls,
                                                 const float* __restrict__ ema_mean,
                                                 const float* __restrict__ inv_std,
                                                 float* __restrict__ out,
                                                 int n_rows) {
  const int wave = threadIdx.x >> 6;
  const int lane = threadIdx.x & 63;
  const int row = blockIdx.x * WPB + wave;
  if (row >= n_rows) return;
  const float* __restrict__ xr = x + (size_t)row * D;
  float* __restrict__ orow = out + (size_t)row * D;

  float xv[VPT], za[VPT];
#pragma unroll
  for (int j = 0; j < 4; ++j) {
    const int c = j * 256 + lane * 4;
    const float4 xx = *reinterpret_cast<const float4*>(xr + c);
    const float4 mm = *reinterpret_cast<const float4*>(ema_mean + c);
    const float4 ss = *reinterpret_cast<const float4*>(inv_std + c);
    xv[4 * j + 0] = xx.x; xv[4 * j + 1] = xx.y;
    xv[4 * j + 2] = xx.z; xv[4 * j + 3] = xx.w;
    za[4 * j + 0] = fabsf(xx.x - mm.x) * ss.x;
    za[4 * j + 1] = fabsf(xx.y - mm.y) * ss.y;
    za[4 * j + 2] = fabsf(xx.z - mm.z) * ss.z;
    za[4 * j + 3] = fabsf(xx.w - mm.w) * ss.w;
  }

  // Row max -> initial upper bracket for the bit-space bisect.
  float m = 0.0f;
#pragma unroll
  for (int i = 0; i < VPT; ++i) m = fmaxf(m, za[i]);
  m = waveReduceMax(m);

  // Exact 32nd-largest via binary search on the (nonnegative) float bit
  // pattern: find max t with count(za >= t) >= TOPK. Early exit when the
  // count is exactly TOPK (then {za >= t} IS the top-K set).
  unsigned lo = 0u, hi = __float_as_uint(m);
  while (lo < hi) {
    const unsigned mid = lo + ((hi - lo + 1u) >> 1);
    const float tm = __uint_as_float(mid);
    int c = 0;
#pragma unroll
    for (int i = 0; i < VPT; ++i) c += (za[i] >= tm) ? 1 : 0;
    c = waveReduceSumI(c);
    if (c >= TOPK) {
      lo = mid;
      if (c == TOPK) break;  // wave-uniform branch: c identical on all lanes
    } else {
      hi = mid - 1u;
    }
  }
  const float t = __uint_as_float(lo);

  // top32_sum = sum of strictly-greater values + ties at t filling the rest.
  float s = 0.0f;
  int cg = 0;
#pragma unroll
  for (int i = 0; i < VPT; ++i) {
    if (za[i] > t) { s += za[i]; ++cg; }
  }
  s = waveReduceSumF(s);
  cg = waveReduceSumI(cg);
  const float topsum = s + (float)(TOPK - cg) * t;
  const float surp = topsum * (1.0f / (float)TOPK);
  const float gate = 1.0f + expf(p_la[0]) * tanhf(expf(p_ls[0]) * surp);

#pragma unroll
  for (int j = 0; j < 4; ++j) {
    const int c = j * 256 + lane * 4;
    float4 o;
    o.x = 0.5f * xv[4 * j + 0] * (1.0f + erff(xv[4 * j + 0] * 0.7071067811865475f)) * gate;
    o.y = 0.5f * xv[4 * j + 1] * (1.0f + erff(xv[4 * j + 1] * 0.7071067811865475f)) * gate;
    o.z = 0.5f * xv[4 * j + 2] * (1.0f + erff(xv[4 * j + 2] * 0.7071067811865475f)) * gate;
    o.w = 0.5f * xv[4 * j + 3] * (1.0f + erff(xv[4 * j + 3] * 0.7071067811865475f)) * gate;
    *reinterpret_cast<float4*>(orow + c) = o;
  }
}

extern "C" void kernel_launch(void* const* d_in, const int* in_sizes, int n_in,
                              void* d_out, int out_size, void* d_ws, size_t ws_size,
                              hipStream_t stream) {
  const float* x    = (const float*)d_in[0];
  const float* la   = (const float*)d_in[1];
  const float* ls   = (const float*)d_in[2];
  const float* mean = (const float*)d_in[3];
  const float* sq   = (const float*)d_in[4];
  float* out = (float*)d_out;
  float* inv_std = (float*)d_ws;  // D floats of scratch

  const int n = in_sizes[0];
  const int n_rows = n / D;

  prep_stats<<<(D + 255) / 256, 256, 0, stream>>>(mean, sq, inv_std);

  const int grid = (n_rows + WPB - 1) / WPB;
  gelu_gate<<<grid, WPB * 64, 0, stream>>>(x, la, ls, mean, inv_std, out, n_rows);
}

// Round 3
// 239.813 us; speedup vs baseline: 1.0182x; 1.0182x over previous
//
#include <hip/hip_runtime.h>
#include <math.h>

#define D 1024
#define TOPK 32
#define VPT 16   // values per lane = D / 64
#define WPB 4    // waves (rows) per block -> 256 threads

typedef float vfloat4 __attribute__((ext_vector_type(4)));  // native vec for nontemporal builtin

__device__ __forceinline__ float waveMax(float v) {
#pragma unroll
  for (int off = 32; off >= 1; off >>= 1)
    v = fmaxf(v, __shfl_xor(v, off, 64));
  return v;
}
__device__ __forceinline__ float waveSumF(float v) {
#pragma unroll
  for (int off = 32; off >= 1; off >>= 1)
    v += __shfl_xor(v, off, 64);
  return v;
}

// Fast GELU: x * sigmoid(1.5957691 * x * (1 + 0.044715 x^2))
// == the tanh-approx GELU rewritten with one exp + one rcp.
// Max abs deviation from exact (erf) GELU ~3e-4 — far under the 0.2 threshold.
__device__ __forceinline__ float fast_gelu(float x) {
  const float x2 = x * x;
  const float p = __builtin_fmaf(0.044715f, x2, 1.0f);
  const float a = -1.5957691216f * x * p;           // -2 * 0.7978845608 * inner
  const float e = __expf(a);                        // v_exp_f32
  const float r = __builtin_amdgcn_rcpf(1.0f + e);  // v_rcp_f32
  return x * r;                                     // x * sigmoid(2y)
}

__global__ __launch_bounds__(256) void prep_stats(const float* __restrict__ ema_mean,
                                                  const float* __restrict__ ema_sq,
                                                  float* __restrict__ inv_std) {
  int i = blockIdx.x * 256 + threadIdx.x;
  if (i < D) {
    float m = ema_mean[i];
    float v = ema_sq[i] - m * m;
    inv_std[i] = rsqrtf(fmaxf(v, 1e-6f));
  }
}

__global__ __launch_bounds__(256, 4) void gelu_gate(const float* __restrict__ x,
                                                    const float* __restrict__ p_la,
                                                    const float* __restrict__ p_ls,
                                                    const float* __restrict__ ema_mean,
                                                    const float* __restrict__ inv_std,
                                                    float* __restrict__ out,
                                                    int n_rows) {
  const int wave = threadIdx.x >> 6;
  const int lane = threadIdx.x & 63;
  const int row = blockIdx.x * WPB + wave;
  if (row >= n_rows) return;
  const float* __restrict__ xr = x + (size_t)row * D;
  float* __restrict__ orow = out + (size_t)row * D;

  float xv[VPT], za[VPT];
#pragma unroll
  for (int j = 0; j < 4; ++j) {
    const int c = j * 256 + lane * 4;
    const float4 xx = *reinterpret_cast<const float4*>(xr + c);
    const float4 mm = *reinterpret_cast<const float4*>(ema_mean + c);
    const float4 ss = *reinterpret_cast<const float4*>(inv_std + c);
    xv[4 * j + 0] = xx.x; xv[4 * j + 1] = xx.y;
    xv[4 * j + 2] = xx.z; xv[4 * j + 3] = xx.w;
    za[4 * j + 0] = fabsf(xx.x - mm.x) * ss.x;
    za[4 * j + 1] = fabsf(xx.y - mm.y) * ss.y;
    za[4 * j + 2] = fabsf(xx.z - mm.z) * ss.z;
    za[4 * j + 3] = fabsf(xx.w - mm.w) * ss.w;
  }

  // Row max -> upper bracket (strictly above V32 via nextafter on the bits).
  float m = 0.0f;
#pragma unroll
  for (int i = 0; i < VPT; ++i) m = fmaxf(m, za[i]);
  m = waveMax(m);

  // Exact 32nd-largest via VALUE-space bisection with ballot counting.
  // Invariants: count(za >= lo) >= TOPK, count(za >= hi) < TOPK.
  // Terminates when no representable float strictly between lo and hi,
  // at which point lo == V32 exactly; or earlier when count == TOPK
  // (then {za >= lo} IS the top-K set). The count lives in SGPRs
  // (v_cmp -> s_bcnt1_b64), so the reduce costs zero VALU and the
  // branch is wave-uniform scalar.
  float lo = 0.0f;
  float hi = __uint_as_float(__float_as_uint(m) + 1u);  // next float above max
  for (;;) {
    const float mid = 0.5f * (lo + hi);
    if (!(mid > lo) || !(mid < hi)) break;  // bracket is 1 ulp: lo == V32
    int c = 0;
#pragma unroll
    for (int i = 0; i < VPT; ++i)
      c += (int)__popcll(__ballot(za[i] >= mid));
    if (c >= TOPK) {
      lo = mid;
      if (c == TOPK) break;  // exact: top-K set found
    } else {
      hi = mid;
    }
  }
  const float t = lo;

  // top32_sum = sum of strictly-greater values + ties at t filling the rest.
  float s = 0.0f;
  int cg = 0;
#pragma unroll
  for (int i = 0; i < VPT; ++i) {
    const bool g = za[i] > t;
    s += g ? za[i] : 0.0f;
    cg += (int)__popcll(__ballot(g));  // wave-total, lands in SGPRs
  }
  s = waveSumF(s);
  const float topsum = s + (float)(TOPK - cg) * t;
  const float surp = topsum * (1.0f / (float)TOPK);
  const float gate = 1.0f + expf(p_la[0]) * tanhf(expf(p_ls[0]) * surp);

#pragma unroll
  for (int j = 0; j < 4; ++j) {
    const int c = j * 256 + lane * 4;
    vfloat4 o;
    o.x = fast_gelu(xv[4 * j + 0]) * gate;
    o.y = fast_gelu(xv[4 * j + 1]) * gate;
    o.z = fast_gelu(xv[4 * j + 2]) * gate;
    o.w = fast_gelu(xv[4 * j + 3]) * gate;
    __builtin_nontemporal_store(o, reinterpret_cast<vfloat4*>(orow + c));
  }
}

extern "C" void kernel_launch(void* const* d_in, const int* in_sizes, int n_in,
                              void* d_out, int out_size, void* d_ws, size_t ws_size,
                              hipStream_t stream) {
  const float* x    = (const float*)d_in[0];
  const float* la   = (const float*)d_in[1];
  const float* ls   = (const float*)d_in[2];
  const float* mean = (const float*)d_in[3];
  const float* sq   = (const float*)d_in[4];
  float* out = (float*)d_out;
  float* inv_std = (float*)d_ws;  // D floats of scratch

  const int n = in_sizes[0];
  const int n_rows = n / D;

  prep_stats<<<(D + 255) / 256, 256, 0, stream>>>(mean, sq, inv_std);

  const int grid = (n_rows + WPB - 1) / WPB;
  gelu_gate<<<grid, WPB * 64, 0, stream>>>(x, la, ls, mean, inv_std, out, n_rows);
}